// Round 3
// baseline (183.863 us; speedup 1.0000x reference)
//
#include <hip/hip_runtime.h>
#include <hip/hip_bf16.h>
#include <cstdint>

typedef __attribute__((ext_vector_type(8))) short bf16x8;
typedef __attribute__((ext_vector_type(4))) short bf16x4;
typedef __attribute__((ext_vector_type(4))) float f32x4;

#define TANH_SCALE 2.8853900817779268f    // 2*log2(e)
#define TANH_UNSCALE 0.34657359027997264f // ln2/2

__device__ __forceinline__ short cvt_bf16(float f) {
  union { float f; uint32_t u; } x; x.f = f;
  uint32_t r = x.u + 0x7FFFu + ((x.u >> 16) & 1u);  // RNE
  return (short)(r >> 16);
}
__device__ __forceinline__ float bf16_to_f(short s) {
  union { uint32_t u; float f; } x; x.u = ((uint32_t)(uint16_t)s) << 16;
  return x.f;
}

// tanh(x) = 1 - 2/(e^{2x}+1); exp2 form never overflows the denominator.
__device__ __forceinline__ float tanh_fast(float x) {
  float e = __builtin_amdgcn_exp2f(x * TANH_SCALE);
  return 1.0f - 2.0f * __builtin_amdgcn_rcpf(e + 1.0f);
}
// sigma-like term: rcp(e^{xs}+1), xs already scaled by TANH_SCALE
__device__ __forceinline__ float sig_pre(float xs) {
  float e = __builtin_amdgcn_exp2f(xs);
  return __builtin_amdgcn_rcpf(e + 1.0f);
}

// Dekker-style f32 -> bf16 hi/lo split, truncating.
__device__ __forceinline__ void split8(float4 a, float4 b, bf16x8& h, bf16x8& l) {
  float fa[8] = {a.x, a.y, a.z, a.w, b.x, b.y, b.z, b.w};
  uint32_t uh[8], ul[8];
  #pragma unroll
  for (int j = 0; j < 8; j++) {
    union { float f; uint32_t u; } x; x.f = fa[j];
    uh[j] = x.u;
    union { uint32_t u; float f; } t; t.u = x.u & 0xffff0000u;
    union { float f; uint32_t u; } y; y.f = fa[j] - t.f;
    ul[j] = y.u;
  }
  union { uint32_t w[4]; bf16x8 v; } H, L;
  #pragma unroll
  for (int j = 0; j < 4; j++) {
    H.w[j] = __builtin_amdgcn_perm(uh[2 * j + 1], uh[2 * j], 0x07060302u);
    L.w[j] = __builtin_amdgcn_perm(ul[2 * j + 1], ul[2 * j], 0x07060302u);
  }
  h = H.v; l = L.v;
}

// ---------- weights/text preprocessing ----------
__global__ __launch_bounds__(256) void k_prep(const float* __restrict__ text,
                                              const float* __restrict__ w1,
                                              const float* __restrict__ w2,
                                              const float* __restrict__ w4,
                                              short* __restrict__ w1h,
                                              short* __restrict__ w1l,
                                              short* __restrict__ w4T,
                                              short* __restrict__ th,
                                              short* __restrict__ tl,
                                              short* __restrict__ w2h,
                                              short* __restrict__ w2l) {
  __shared__ float tile[32][33];
  int bid = blockIdx.x;
  if (bid < 256) {
    int idx = bid;
    int r0 = (idx & 31) * 32, c0 = (idx >> 5) * 32;
    int j = threadIdx.x & 31, i0 = threadIdx.x >> 5;
    #pragma unroll
    for (int i = i0; i < 32; i += 8) tile[i][j] = w1[(size_t)(r0 + i) * 256 + c0 + j];
    __syncthreads();
    #pragma unroll
    for (int i = i0; i < 32; i += 8) {
      float v = tile[j][i];
      short h = cvt_bf16(v);
      w1h[(size_t)(c0 + i) * 1024 + r0 + j] = h;
      w1l[(size_t)(c0 + i) * 1024 + r0 + j] = cvt_bf16(v - bf16_to_f(h));
    }
  } else if (bid < 768) {
    int idx = bid - 256;
    int r0 = (idx & 31) * 32, c0 = (idx >> 5) * 32;
    int j = threadIdx.x & 31, i0 = threadIdx.x >> 5;
    #pragma unroll
    for (int i = i0; i < 32; i += 8) {
      int c = c0 + j;
      tile[i][j] = (c < 500) ? w4[(size_t)(r0 + i) * 500 + c] : 0.f;
    }
    __syncthreads();
    #pragma unroll
    for (int i = i0; i < 32; i += 8)
      w4T[(size_t)(c0 + i) * 1024 + r0 + j] = cvt_bf16(tile[j][i]);
  } else if (bid < 928) {
    int idx = bid - 768;
    int row = idx * 4 + (threadIdx.x >> 6);
    int cl = threadIdx.x & 63;
    const float* trow = text + (size_t)row * 300;
    short* hrow = th + (size_t)row * 320;
    short* lrow = tl + (size_t)row * 320;
    #pragma unroll
    for (int c0 = 0; c0 < 320; c0 += 64) {
      int c = c0 + cl;
      float v = (c < 300) ? trow[c] : 0.f;
      short h = cvt_bf16(v);
      hrow[c] = h;
      lrow[c] = cvt_bf16(v - bf16_to_f(h));
    }
  } else {
    int idx = bid - 928;                  // 0..79
    int rt = idx % 10, ct = idx / 10;
    int r0 = rt * 32, c0 = ct * 32;
    int j = threadIdx.x & 31, i0 = threadIdx.x >> 5;
    #pragma unroll
    for (int i = i0; i < 32; i += 8) {
      int r = r0 + i;
      tile[i][j] = (r < 300) ? w2[(size_t)r * 256 + c0 + j] : 0.f;
    }
    __syncthreads();
    #pragma unroll
    for (int i = i0; i < 32; i += 8) {
      float v = tile[j][i];               // = w2[r0+j][c0+i]
      short h = cvt_bf16(v);
      w2h[(size_t)(c0 + i) * 320 + r0 + j] = h;
      w2l[(size_t)(c0 + i) * 320 + r0 + j] = cvt_bf16(v - bf16_to_f(h));
    }
  }
}

// async global->LDS, 16 B per lane; lds base must be wave-uniform
__device__ __forceinline__ void load_lds16(void* lds, const void* g) {
  __builtin_amdgcn_global_load_lds(
      (const __attribute__((address_space(1))) void*)g,
      (__attribute__((address_space(3))) void*)lds, 16, 0, 0);
}

// ---------- merged GEMM dispatch ----------
// blocks [0,512): e = video @ w1 split-bf16, 64x64 tile, BK=64, FULL K=1024 (no split-K).
//   128 m-tiles x 4 n-tiles = 512 blocks = 2/CU — same occupancy/overlap as the proven
//   R0 structure, but e is written ONCE as f32 (8.4 MB instead of 16.8 MB partials).
//   A (video) read f32 and hi/lo-split in-register, ds_write to LDS; w1 staged via
//   global_load_lds.
// blocks [512,552): fb = text @ w2 (unchanged).
__global__ __launch_bounds__(256) void k_gemm_big(const float* __restrict__ video,
                                                  const short* __restrict__ w1h,
                                                  const short* __restrict__ w1l,
                                                  const short* __restrict__ th,
                                                  const short* __restrict__ tl,
                                                  const short* __restrict__ w2h,
                                                  const short* __restrict__ w2l,
                                                  float* __restrict__ ebuf,
                                                  float* __restrict__ fbuf) {
  __shared__ __align__(16) char smem[36864];
  int bid = blockIdx.x;
  int tid = threadIdx.x, lane = tid & 63, wave = tid >> 6;
  int mrow = lane & 15, quad = lane >> 4;

  if (bid < 512) {
    short (*Ash)[64] = (short (*)[64])(smem);          // 8 KB
    short (*Asl)[64] = (short (*)[64])(smem + 8192);   // 8 KB
    short (*Bsh)[64] = (short (*)[64])(smem + 16384);  // 8 KB
    short (*Bsl)[64] = (short (*)[64])(smem + 24576);  // 8 KB
    int m0 = (bid >> 2) * 64, n0 = (bid & 3) * 64;
    int wm = (wave & 1) * 32, wn = (wave >> 1) * 32;
    int lrow = lane >> 3, lseg = (lane & 7) * 8;

    f32x4 acc[2][2];
    #pragma unroll
    for (int i = 0; i < 2; i++)
      #pragma unroll
      for (int j = 0; j < 2; j++) acc[i][j] = (f32x4){0.f, 0.f, 0.f, 0.f};

    // A f32 tile: 64 rows x 64 K = 512 slots of 8 floats; 2 slots per thread.
    auto loadA = [&](int k0, float4* va) {
      #pragma unroll
      for (int it = 0; it < 2; it++) {
        int idx = it * 256 + tid;
        const float* src = video + (size_t)(m0 + (idx >> 3)) * 1024 + k0 + (idx & 7) * 8;
        va[it * 2]     = *(const float4*)src;
        va[it * 2 + 1] = *(const float4*)(src + 4);
      }
    };

    float4 va[4];
    loadA(0, va);

    for (int t = 0; t < 16; t++) {
      int k0 = t * 64;
      bf16x8 hi[2], lo[2];
      #pragma unroll
      for (int it = 0; it < 2; it++) split8(va[it * 2], va[it * 2 + 1], hi[it], lo[it]);
      __syncthreads();                   // all waves done reading previous tiles
      #pragma unroll
      for (int it = 0; it < 2; it++) {
        int idx = it * 256 + tid;
        *(bf16x8*)&Ash[idx >> 3][(idx & 7) * 8] = hi[it];
        *(bf16x8*)&Asl[idx >> 3][(idx & 7) * 8] = lo[it];
      }
      #pragma unroll
      for (int i = 0; i < 2; i++) {      // B hi/lo: 8 chunks, 2 per wave
        int c = wave * 2 + i;
        size_t go = (size_t)(n0 + c * 8 + lrow) * 1024 + k0 + lseg;
        load_lds16(&Bsh[c * 8][0], w1h + go);
        load_lds16(&Bsl[c * 8][0], w1l + go);
      }
      if (t + 1 < 16) loadA(k0 + 64, va);
      __syncthreads();                   // drains glds + A writes (implicit vmcnt/lgkm 0)
      #pragma unroll
      for (int ks = 0; ks < 2; ks++) {
        int kk = ks * 32 + quad * 8;
        bf16x8 ah[2], al[2], bh[2], bl[2];
        #pragma unroll
        for (int i = 0; i < 2; i++) {
          ah[i] = *(const bf16x8*)&Ash[wm + i * 16 + mrow][kk];
          al[i] = *(const bf16x8*)&Asl[wm + i * 16 + mrow][kk];
        }
        #pragma unroll
        for (int j = 0; j < 2; j++) {
          bh[j] = *(const bf16x8*)&Bsh[wn + j * 16 + mrow][kk];
          bl[j] = *(const bf16x8*)&Bsl[wn + j * 16 + mrow][kk];
        }
        #pragma unroll
        for (int i = 0; i < 2; i++)
          #pragma unroll
          for (int j = 0; j < 2; j++) {
            acc[i][j] = __builtin_amdgcn_mfma_f32_16x16x32_bf16(ah[i], bh[j], acc[i][j], 0, 0, 0);
            acc[i][j] = __builtin_amdgcn_mfma_f32_16x16x32_bf16(ah[i], bl[j], acc[i][j], 0, 0, 0);
            acc[i][j] = __builtin_amdgcn_mfma_f32_16x16x32_bf16(al[i], bh[j], acc[i][j], 0, 0, 0);
          }
      }
    }
    int rbase = quad * 4;
    #pragma unroll
    for (int i = 0; i < 2; i++)
      #pragma unroll
      for (int j = 0; j < 2; j++) {
        int col = n0 + wn + j * 16 + mrow;
        #pragma unroll
        for (int r = 0; r < 4; r++) {
          int row = m0 + wm + i * 16 + rbase + r;
          ebuf[(size_t)row * 256 + col] = acc[i][j][r];
        }
      }
  } else {
    // fb GEMM: M=640, N=256, K=320, 64x64 tiles, VALU-staged split-bf16
    short (*Ash)[72] = (short (*)[72])(smem);
    short (*Asl)[72] = (short (*)[72])(smem + 9216);
    short (*Bsh)[72] = (short (*)[72])(smem + 18432);
    short (*Bsl)[72] = (short (*)[72])(smem + 27648);
    int idx = bid - 512;                  // 0..39
    int m0 = (idx % 10) * 64, n0 = (idx / 10) * 64;
    int wm = (wave & 1) * 32, wn = (wave >> 1) * 32;
    int srow = tid >> 3, sseg = (tid & 7) * 8;
    f32x4 acc[2][2];
    #pragma unroll
    for (int i = 0; i < 2; i++)
      #pragma unroll
      for (int j = 0; j < 2; j++) acc[i][j] = (f32x4){0.f, 0.f, 0.f, 0.f};

    for (int k0 = 0; k0 < 320; k0 += 64) {
      size_t aoff0 = (size_t)(m0 + srow) * 320 + k0 + sseg;
      size_t aoff1 = aoff0 + (size_t)32 * 320;
      size_t boff0 = (size_t)(n0 + srow) * 320 + k0 + sseg;
      size_t boff1 = boff0 + (size_t)32 * 320;
      bf16x8 a0h = *(const bf16x8*)(th + aoff0);
      bf16x8 a1h = *(const bf16x8*)(th + aoff1);
      bf16x8 a0l = *(const bf16x8*)(tl + aoff0);
      bf16x8 a1l = *(const bf16x8*)(tl + aoff1);
      bf16x8 b0h = *(const bf16x8*)(w2h + boff0);
      bf16x8 b1h = *(const bf16x8*)(w2h + boff1);
      bf16x8 b0l = *(const bf16x8*)(w2l + boff0);
      bf16x8 b1l = *(const bf16x8*)(w2l + boff1);
      __syncthreads();
      *(bf16x8*)&Ash[srow][sseg] = a0h;  *(bf16x8*)&Ash[srow + 32][sseg] = a1h;
      *(bf16x8*)&Asl[srow][sseg] = a0l;  *(bf16x8*)&Asl[srow + 32][sseg] = a1l;
      *(bf16x8*)&Bsh[srow][sseg] = b0h;  *(bf16x8*)&Bsh[srow + 32][sseg] = b1h;
      *(bf16x8*)&Bsl[srow][sseg] = b0l;  *(bf16x8*)&Bsl[srow + 32][sseg] = b1l;
      __syncthreads();
      #pragma unroll
      for (int ks = 0; ks < 2; ks++) {
        int kk = ks * 32 + quad * 8;
        bf16x8 ah[2], al[2], bh[2], bl[2];
        ah[0] = *(const bf16x8*)&Ash[wm + mrow][kk];
        ah[1] = *(const bf16x8*)&Ash[wm + 16 + mrow][kk];
        al[0] = *(const bf16x8*)&Asl[wm + mrow][kk];
        al[1] = *(const bf16x8*)&Asl[wm + 16 + mrow][kk];
        bh[0] = *(const bf16x8*)&Bsh[wn + mrow][kk];
        bh[1] = *(const bf16x8*)&Bsh[wn + 16 + mrow][kk];
        bl[0] = *(const bf16x8*)&Bsl[wn + mrow][kk];
        bl[1] = *(const bf16x8*)&Bsl[wn + 16 + mrow][kk];
        #pragma unroll
        for (int i = 0; i < 2; i++)
          #pragma unroll
          for (int j = 0; j < 2; j++) {
            acc[i][j] = __builtin_amdgcn_mfma_f32_16x16x32_bf16(ah[i], bh[j], acc[i][j], 0, 0, 0);
            acc[i][j] = __builtin_amdgcn_mfma_f32_16x16x32_bf16(ah[i], bl[j], acc[i][j], 0, 0, 0);
            acc[i][j] = __builtin_amdgcn_mfma_f32_16x16x32_bf16(al[i], bh[j], acc[i][j], 0, 0, 0);
          }
      }
    }
    int rbase = quad * 4;
    #pragma unroll
    for (int i = 0; i < 2; i++)
      #pragma unroll
      for (int j = 0; j < 2; j++) {
        int col = n0 + wn + j * 16 + mrow;
        #pragma unroll
        for (int r = 0; r < 4; r++) {
          int row = m0 + wm + i * 16 + rbase + r;
          fbuf[(size_t)row * 256 + col] = acc[i][j][r];
        }
      }
  }
}

// ---------- final GEMM: 128x64 tile, BK=64, LDS double-buffer, counted vmcnt ----------
__global__ __launch_bounds__(256) void k_gemm_f(const short* __restrict__ A,
                                                const short* __restrict__ BT,
                                                const float* __restrict__ bias,
                                                float* __restrict__ C,
                                                int K, int ldc, int nstore) {
  __shared__ __align__(16) short As[2][128][64];  // 32 KB
  __shared__ __align__(16) short Bs[2][64][64];   // 16 KB
  int m0 = blockIdx.x * 128, n0 = blockIdx.y * 64;
  int tid = threadIdx.x, lane = tid & 63, wave = tid >> 6;
  int wm = wave * 32;
  int mrow = lane & 15, quad = lane >> 4;
  int lrow = lane >> 3, lseg = (lane & 7) * 8;

  f32x4 acc[2][4];
  #pragma unroll
  for (int i = 0; i < 2; i++)
    #pragma unroll
    for (int j = 0; j < 4; j++) acc[i][j] = (f32x4){0.f, 0.f, 0.f, 0.f};

  auto stage = [&](int k0, int buf) {    // 6 vm ops per wave
    #pragma unroll
    for (int i = 0; i < 4; i++) {
      int c = wave * 4 + i;
      load_lds16(&As[buf][c * 8][0], A + (size_t)(m0 + c * 8 + lrow) * K + k0 + lseg);
    }
    #pragma unroll
    for (int i = 0; i < 2; i++) {
      int c = wave * 2 + i;
      load_lds16(&Bs[buf][c * 8][0], BT + (size_t)(n0 + c * 8 + lrow) * K + k0 + lseg);
    }
  };

  int NT = K >> 6;
  stage(0, 0);
  for (int t = 0; t < NT; t++) {
    int cur = t & 1;
    if (t + 1 < NT) {
      stage((t + 1) << 6, cur ^ 1);      // stays in flight across the barrier
      asm volatile("s_waitcnt vmcnt(6)" ::: "memory");   // buf[cur]'s 6 loads retired
    } else {
      asm volatile("s_waitcnt vmcnt(0)" ::: "memory");
    }
    __builtin_amdgcn_s_barrier();
    #pragma unroll
    for (int ks = 0; ks < 2; ks++) {
      int kk = ks * 32 + quad * 8;
      bf16x8 af[2], bf[4];
      #pragma unroll
      for (int i = 0; i < 2; i++) af[i] = *(const bf16x8*)&As[cur][wm + i * 16 + mrow][kk];
      #pragma unroll
      for (int j = 0; j < 4; j++) bf[j] = *(const bf16x8*)&Bs[cur][j * 16 + mrow][kk];
      #pragma unroll
      for (int i = 0; i < 2; i++)
        #pragma unroll
        for (int j = 0; j < 4; j++)
          acc[i][j] = __builtin_amdgcn_mfma_f32_16x16x32_bf16(af[i], bf[j], acc[i][j], 0, 0, 0);
    }
    __builtin_amdgcn_s_barrier();        // all reads of buf[cur] done before re-stage
  }
  int rbase = quad * 4;
  #pragma unroll
  for (int i = 0; i < 2; i++)
    #pragma unroll
    for (int j = 0; j < 4; j++) {
      int col = n0 + j * 16 + mrow;
      if (col < nstore) {
        float bv = bias[col];
        #pragma unroll
        for (int r = 0; r < 4; r++) {
          int row = m0 + wm + i * 16 + rbase + r;
          C[(size_t)row * ldc + col] = acc[i][j][r] + bv;
        }
      }
    }
}

// ---------- fused middle: single e input; logits via -2*w3*sigma ----------
__global__ __launch_bounds__(512) void k_middle(const float* __restrict__ eb,
                                                const float* __restrict__ fb,
                                                const float* __restrict__ w3,
                                                const float* __restrict__ bias,
                                                short* __restrict__ cont) {
  __shared__ __align__(16) float fbs[40 * 256];  // 40 KB: (f+bias)*TANH_SCALE
  __shared__ float lg[16][40];
  __shared__ float attn[16][40];
  int tid = threadIdx.x, wave = tid >> 6, lane = tid & 63;
  int la = lane & 31, half = lane >> 5;
  int row0 = blockIdx.x * 16;
  int b = row0 >> 9;          // 512 rows per batch; 16 | 512 so block is batch-pure
  int lgrow = wave + (half ? 8 : 0);
  int myrow = row0 + lgrow;

  const float4* fsrc = (const float4*)(fb + (size_t)b * 40 * 256);
  const float4* bias4 = (const float4*)bias;
  for (int i = tid; i < 40 * 64; i += 512) {
    float4 v = fsrc[i];
    float4 bb = bias4[i & 63];
    v.x = (v.x + bb.x) * TANH_SCALE; v.y = (v.y + bb.y) * TANH_SCALE;
    v.z = (v.z + bb.z) * TANH_SCALE; v.w = (v.w + bb.w) * TANH_SCALE;
    ((float4*)fbs)[i] = v;
  }
  __syncthreads();

  int a0 = la * 8;
  size_t eoff = (size_t)myrow * 256 + a0;
  float4 e0 = *(const float4*)(eb + eoff);
  float4 e1 = *(const float4*)(eb + eoff + 4);
  float4 w30 = *(const float4*)(w3 + a0);
  float4 w31 = *(const float4*)(w3 + a0 + 4);
  w30.x *= -2.f; w30.y *= -2.f; w30.z *= -2.f; w30.w *= -2.f;
  w31.x *= -2.f; w31.y *= -2.f; w31.z *= -2.f; w31.w *= -2.f;
  float4 bv0 = *(const float4*)(bias + a0);
  float4 bv1 = *(const float4*)(bias + a0 + 4);
  float4 es0, es1;
  es0.x = e0.x * TANH_SCALE; es0.y = e0.y * TANH_SCALE;
  es0.z = e0.z * TANH_SCALE; es0.w = e0.w * TANH_SCALE;
  es1.x = e1.x * TANH_SCALE; es1.y = e1.y * TANH_SCALE;
  es1.z = e1.z * TANH_SCALE; es1.w = e1.w * TANH_SCALE;

  for (int tc = 0; tc < 40; tc += 4) {
    float p[4];
    #pragma unroll
    for (int u = 0; u < 4; u++) {
      const float* fr = &fbs[(tc + u) * 256 + a0];
      float4 f0 = *(const float4*)fr;
      float4 f1 = *(const float4*)(fr + 4);
      p[u] = sig_pre(es0.x + f0.x) * w30.x + sig_pre(es0.y + f0.y) * w30.y
           + sig_pre(es0.z + f0.z) * w30.z + sig_pre(es0.w + f0.w) * w30.w
           + sig_pre(es1.x + f1.x) * w31.x + sig_pre(es1.y + f1.y) * w31.y
           + sig_pre(es1.z + f1.z) * w31.z + sig_pre(es1.w + f1.w) * w31.w;
    }
    #pragma unroll
    for (int s = 16; s >= 1; s >>= 1) {
      #pragma unroll
      for (int u = 0; u < 4; u++) p[u] += __shfl_xor(p[u], s, 64);
    }
    if (la == 0) {
      #pragma unroll
      for (int u = 0; u < 4; u++) lg[lgrow][tc + u] = p[u];
    }
  }

  auto softmax_row = [&](int r) {
    float x = (lane < 40) ? lg[r][lane] : -3.0e38f;
    float m = x;
    #pragma unroll
    for (int s = 32; s >= 1; s >>= 1) m = fmaxf(m, __shfl_xor(m, s, 64));
    float ex = (lane < 40) ? __builtin_amdgcn_exp2f((x - m) * 1.4426950408889634f) : 0.f;
    float ssum = ex;
    #pragma unroll
    for (int s = 32; s >= 1; s >>= 1) ssum += __shfl_xor(ssum, s, 64);
    if (lane < 40) attn[r][lane] = ex * __builtin_amdgcn_rcpf(ssum);
  };
  softmax_row(wave);
  softmax_row(wave + 8);

  float ac[8] = {0.f,0.f,0.f,0.f,0.f,0.f,0.f,0.f};
  for (int t = 0; t < 40; t++) {
    float w = attn[lgrow][t];
    const float* fr = &fbs[t * 256 + a0];
    float4 f0 = *(const float4*)fr;
    float4 f1 = *(const float4*)(fr + 4);
    ac[0] += w * f0.x; ac[1] += w * f0.y; ac[2] += w * f0.z; ac[3] += w * f0.w;
    ac[4] += w * f1.x; ac[5] += w * f1.y; ac[6] += w * f1.z; ac[7] += w * f1.w;
  }
  float tx[8];
  tx[0] = ac[0] * TANH_UNSCALE - bv0.x; tx[1] = ac[1] * TANH_UNSCALE - bv0.y;
  tx[2] = ac[2] * TANH_UNSCALE - bv0.z; tx[3] = ac[3] * TANH_UNSCALE - bv0.w;
  tx[4] = ac[4] * TANH_UNSCALE - bv1.x; tx[5] = ac[5] * TANH_UNSCALE - bv1.y;
  tx[6] = ac[6] * TANH_UNSCALE - bv1.z; tx[7] = ac[7] * TANH_UNSCALE - bv1.w;
  float ev[8] = {e0.x, e0.y, e0.z, e0.w, e1.x, e1.y, e1.z, e1.w};

  short* crow = cont + (size_t)myrow * 1024 + a0;
  auto st8 = [&](int off, const float* v) {
    bf16x8 pk;
    #pragma unroll
    for (int i = 0; i < 8; i++) pk[i] = cvt_bf16(v[i]);
    *(bf16x8*)(crow + off) = pk;
  };
  float s0[8], s1[8], s2[8], s3[8];
  #pragma unroll
  for (int i = 0; i < 8; i++) {
    s0[i] = tanh_fast(ev[i]);
    s1[i] = tanh_fast(tx[i]);
    s2[i] = tanh_fast(ev[i] * tx[i]);
    s3[i] = tanh_fast(ev[i] - tx[i]);
  }
  st8(0, s0); st8(256, s1); st8(512, s2); st8(768, s3);
}

extern "C" void kernel_launch(void* const* d_in, const int* in_sizes, int n_in,
                              void* d_out, int out_size, void* d_ws, size_t ws_size,
                              hipStream_t stream) {
  const float* video = (const float*)d_in[0];  // 16x512x1024
  const float* text  = (const float*)d_in[1];  // 16x40x300
  const float* w1    = (const float*)d_in[2];  // 1024x256
  const float* w2    = (const float*)d_in[3];  // 300x256
  const float* w3    = (const float*)d_in[4];  // 256
  const float* bias  = (const float*)d_in[5];  // 256
  const float* w4    = (const float*)d_in[6];  // 1024x500
  const float* b4    = (const float*)d_in[7];  // 500
  float* out = (float*)d_out;                  // 16x512x500
  char* ws = (char*)d_ws;

  short* contbuf  = (short*)(ws);                        // 8192x1024 bf16 = 16,777,216
  short* w1T_hi   = (short*)(ws + 16777216);             // 256x1024 bf16 = 524,288
  short* w1T_lo   = (short*)(ws + 17301504);             // 524,288
  short* w4T      = (short*)(ws + 17825792);             // 512x1024 bf16 = 1,048,576
  float* fbuf     = (float*)(ws + 18874368);             // 16x40x256 f32 = 655,360
  float* ebuf     = (float*)(ws + 19529728);             // 8192x256 f32 = 8,388,608
  short* text_hi  = (short*)(ws + 36306944);             // 640x320 bf16 = 409,600
  short* text_lo  = (short*)(ws + 36716544);             // 409,600
  short* w2T_hi   = (short*)(ws + 37126144);             // 256x320 bf16 = 204,800
  short* w2T_lo   = (short*)(ws + 37330944);             // 204,800

  k_prep<<<1008, 256, 0, stream>>>(text, w1, w2, w4,
                                   w1T_hi, w1T_lo, w4T,
                                   text_hi, text_lo, w2T_hi, w2T_lo);
  // e = video @ w1 (full-K, single f32 output)  +  fb = text @ w2
  k_gemm_big<<<552, 256, 0, stream>>>(video, w1T_hi, w1T_lo,
                                      text_hi, text_lo, w2T_hi, w2T_lo,
                                      ebuf, fbuf);
  k_middle<<<512, 512, 0, stream>>>(ebuf, fbuf, w3, bias, contbuf);
  k_gemm_f<<<dim3(64, 8), 256, 0, stream>>>(contbuf, w4T, b4, out, 1024, 500, 500);
}

// Round 4
// 155.710 us; speedup vs baseline: 1.1808x; 1.1808x over previous
//
#include <hip/hip_runtime.h>
#include <hip/hip_bf16.h>
#include <cstdint>

typedef __attribute__((ext_vector_type(8))) short bf16x8;
typedef __attribute__((ext_vector_type(4))) short bf16x4;
typedef __attribute__((ext_vector_type(4))) float f32x4;

#define TANH_SCALE 2.8853900817779268f    // 2*log2(e)
#define TANH_UNSCALE 0.34657359027997264f // ln2/2

__device__ __forceinline__ short cvt_bf16(float f) {
  union { float f; uint32_t u; } x; x.f = f;
  uint32_t r = x.u + 0x7FFFu + ((x.u >> 16) & 1u);  // RNE
  return (short)(r >> 16);
}
__device__ __forceinline__ float bf16_to_f(short s) {
  union { uint32_t u; float f; } x; x.u = ((uint32_t)(uint16_t)s) << 16;
  return x.f;
}

// tanh(x) = 1 - 2/(e^{2x}+1); exp2 form never overflows the denominator.
__device__ __forceinline__ float tanh_fast(float x) {
  float e = __builtin_amdgcn_exp2f(x * TANH_SCALE);
  return 1.0f - 2.0f * __builtin_amdgcn_rcpf(e + 1.0f);
}
// sigma-like term: rcp(e^{xs}+1), xs already scaled by TANH_SCALE
__device__ __forceinline__ float sig_pre(float xs) {
  float e = __builtin_amdgcn_exp2f(xs);
  return __builtin_amdgcn_rcpf(e + 1.0f);
}

// Dekker-style f32 -> bf16 hi/lo split, truncating.
__device__ __forceinline__ void split8(float4 a, float4 b, bf16x8& h, bf16x8& l) {
  float fa[8] = {a.x, a.y, a.z, a.w, b.x, b.y, b.z, b.w};
  uint32_t uh[8], ul[8];
  #pragma unroll
  for (int j = 0; j < 8; j++) {
    union { float f; uint32_t u; } x; x.f = fa[j];
    uh[j] = x.u;
    union { uint32_t u; float f; } t; t.u = x.u & 0xffff0000u;
    union { float f; uint32_t u; } y; y.f = fa[j] - t.f;
    ul[j] = y.u;
  }
  union { uint32_t w[4]; bf16x8 v; } H, L;
  #pragma unroll
  for (int j = 0; j < 4; j++) {
    H.w[j] = __builtin_amdgcn_perm(uh[2 * j + 1], uh[2 * j], 0x07060302u);
    L.w[j] = __builtin_amdgcn_perm(ul[2 * j + 1], ul[2 * j], 0x07060302u);
  }
  h = H.v; l = L.v;
}

// ---------- weights/text preprocessing ----------
__global__ __launch_bounds__(256) void k_prep(const float* __restrict__ text,
                                              const float* __restrict__ w1,
                                              const float* __restrict__ w2,
                                              const float* __restrict__ w4,
                                              short* __restrict__ w1h,
                                              short* __restrict__ w1l,
                                              short* __restrict__ w4T,
                                              short* __restrict__ th,
                                              short* __restrict__ tl,
                                              short* __restrict__ w2h,
                                              short* __restrict__ w2l) {
  __shared__ float tile[32][33];
  int bid = blockIdx.x;
  if (bid < 256) {
    int idx = bid;
    int r0 = (idx & 31) * 32, c0 = (idx >> 5) * 32;
    int j = threadIdx.x & 31, i0 = threadIdx.x >> 5;
    #pragma unroll
    for (int i = i0; i < 32; i += 8) tile[i][j] = w1[(size_t)(r0 + i) * 256 + c0 + j];
    __syncthreads();
    #pragma unroll
    for (int i = i0; i < 32; i += 8) {
      float v = tile[j][i];
      short h = cvt_bf16(v);
      w1h[(size_t)(c0 + i) * 1024 + r0 + j] = h;
      w1l[(size_t)(c0 + i) * 1024 + r0 + j] = cvt_bf16(v - bf16_to_f(h));
    }
  } else if (bid < 768) {
    int idx = bid - 256;
    int r0 = (idx & 31) * 32, c0 = (idx >> 5) * 32;
    int j = threadIdx.x & 31, i0 = threadIdx.x >> 5;
    #pragma unroll
    for (int i = i0; i < 32; i += 8) {
      int c = c0 + j;
      tile[i][j] = (c < 500) ? w4[(size_t)(r0 + i) * 500 + c] : 0.f;
    }
    __syncthreads();
    #pragma unroll
    for (int i = i0; i < 32; i += 8)
      w4T[(size_t)(c0 + i) * 1024 + r0 + j] = cvt_bf16(tile[j][i]);
  } else if (bid < 928) {
    int idx = bid - 768;
    int row = idx * 4 + (threadIdx.x >> 6);
    int cl = threadIdx.x & 63;
    const float* trow = text + (size_t)row * 300;
    short* hrow = th + (size_t)row * 320;
    short* lrow = tl + (size_t)row * 320;
    #pragma unroll
    for (int c0 = 0; c0 < 320; c0 += 64) {
      int c = c0 + cl;
      float v = (c < 300) ? trow[c] : 0.f;
      short h = cvt_bf16(v);
      hrow[c] = h;
      lrow[c] = cvt_bf16(v - bf16_to_f(h));
    }
  } else {
    int idx = bid - 928;                  // 0..79
    int rt = idx % 10, ct = idx / 10;
    int r0 = rt * 32, c0 = ct * 32;
    int j = threadIdx.x & 31, i0 = threadIdx.x >> 5;
    #pragma unroll
    for (int i = i0; i < 32; i += 8) {
      int r = r0 + i;
      tile[i][j] = (r < 300) ? w2[(size_t)r * 256 + c0 + j] : 0.f;
    }
    __syncthreads();
    #pragma unroll
    for (int i = i0; i < 32; i += 8) {
      float v = tile[j][i];               // = w2[r0+j][c0+i]
      short h = cvt_bf16(v);
      w2h[(size_t)(c0 + i) * 320 + r0 + j] = h;
      w2l[(size_t)(c0 + i) * 320 + r0 + j] = cvt_bf16(v - bf16_to_f(h));
    }
  }
}

// async global->LDS, 16 B per lane; lds base must be wave-uniform
__device__ __forceinline__ void load_lds16(void* lds, const void* g) {
  __builtin_amdgcn_global_load_lds(
      (const __attribute__((address_space(1))) void*)g,
      (__attribute__((address_space(3))) void*)lds, 16, 0, 0);
}

// ---------- merged GEMM dispatch (R2 structure + T2 XOR swizzle) ----------
// blocks [0,512): e = video @ w1 split-bf16, 128x64 tile, BK=64, split-K=2.
//   LDS tiles XOR-swizzled: 16-B slot s of row r lives at phys slot s^(r&7).
//   glds-staged B achieves this by pre-swizzling the per-lane GLOBAL k-segment
//   (linear dest, rule: linear dest + inv-swz source + swz read); reg-staged A
//   swizzles the ds_write address. Frag reads apply the same XOR -> bank-conflict-free.
// blocks [512,552): fb = text @ w2 (tiny, padded LDS, unchanged).
__global__ __launch_bounds__(256) void k_gemm_big(const float* __restrict__ video,
                                                  const short* __restrict__ w1h,
                                                  const short* __restrict__ w1l,
                                                  const short* __restrict__ th,
                                                  const short* __restrict__ tl,
                                                  const short* __restrict__ w2h,
                                                  const short* __restrict__ w2l,
                                                  float* __restrict__ eparts,
                                                  float* __restrict__ fbuf) {
  __shared__ __align__(16) char smem[65536];
  int bid = blockIdx.x;
  int tid = threadIdx.x, lane = tid & 63, wave = tid >> 6;
  int mrow = lane & 15, quad = lane >> 4;

  if (bid < 512) {
    short (*Ash)[64] = (short (*)[64])(smem);          // 16 KB
    short (*Asl)[64] = (short (*)[64])(smem + 16384);  // 16 KB
    // B double-buffered: Bh[buf] at 32768 + buf*8192, Bl[buf] at 49152 + buf*8192
    int m0 = (bid & 63) * 128, n0 = ((bid >> 6) & 3) * 64;
    int z = bid >> 8;
    int kz0 = z * 512;
    int wm = wave * 32;
    int lrow = lane >> 3;                       // 0..7
    int lsegsw = ((lane & 7) ^ lrow) * 8;       // pre-swizzled global k-segment

    f32x4 acc[2][4];
    #pragma unroll
    for (int i = 0; i < 2; i++)
      #pragma unroll
      for (int j = 0; j < 4; j++) acc[i][j] = (f32x4){0.f, 0.f, 0.f, 0.f};

    // stage B K-slice k0 into buffer buf (4 glds per wave), pre-swizzled source
    auto stageB = [&](int k0, int buf) {
      short* Bh = (short*)(smem + 32768 + buf * 8192);
      short* Bl = (short*)(smem + 49152 + buf * 8192);
      #pragma unroll
      for (int i = 0; i < 2; i++) {
        int c = wave * 2 + i;
        size_t go = (size_t)(n0 + c * 8 + lrow) * 1024 + k0 + lsegsw;
        load_lds16(Bh + (size_t)(c * 8) * 64, w1h + go);
        load_lds16(Bl + (size_t)(c * 8) * 64, w1l + go);
      }
    };
    auto loadA = [&](int k0, float4* va) {
      #pragma unroll
      for (int it = 0; it < 4; it++) {
        int idx = it * 256 + tid;
        const float* src = video + (size_t)(m0 + (idx >> 3)) * 1024 + k0 + (idx & 7) * 8;
        va[it * 2]     = *(const float4*)src;
        va[it * 2 + 1] = *(const float4*)(src + 4);
      }
    };

    float4 va[8];
    stageB(kz0, 0);          // 4 vm ops
    loadA(kz0, va);          // 8 vm ops

    for (int t = 0; t < 8; t++) {
      int k0 = kz0 + t * 64;
      int cur = t & 1;
      bf16x8 hi[4], lo[4];
      #pragma unroll
      for (int it = 0; it < 4; it++) split8(va[it * 2], va[it * 2 + 1], hi[it], lo[it]);
      __builtin_amdgcn_s_barrier();      // all waves finished compute(t-1)
      #pragma unroll
      for (int it = 0; it < 4; it++) {
        int idx = it * 256 + tid;
        int row = idx >> 3;
        int sw = ((idx & 7) ^ (row & 7)) * 8;   // swizzled slot
        *(bf16x8*)&Ash[row][sw] = hi[it];
        *(bf16x8*)&Asl[row][sw] = lo[it];
      }
      if (t + 1 < 8) {
        stageB(k0 + 64, cur ^ 1);        // 4 vm ops — stays in flight across barrier
        loadA(k0 + 64, va);              // 8 vm ops — stays in flight across barrier
        asm volatile("s_waitcnt vmcnt(12)" ::: "memory");
      } else {
        asm volatile("s_waitcnt vmcnt(0)" ::: "memory");
      }
      asm volatile("s_waitcnt lgkmcnt(0)" ::: "memory");  // A ds_writes done
      __builtin_amdgcn_s_barrier();      // raw: in-flight loads NOT drained
      const short* Bh = (const short*)(smem + 32768 + cur * 8192);
      const short* Bl = (const short*)(smem + 49152 + cur * 8192);
      int rsw = mrow & 7;                // row&7 for all frag rows (wm,i*16,j*16 mult of 8)
      #pragma unroll
      for (int ks = 0; ks < 2; ks++) {
        int slot = ks * 4 + quad;
        int kko = ((slot ^ rsw) & 7) * 8;
        bf16x8 ah[2], al[2], bh[4], bl[4];
        #pragma unroll
        for (int i = 0; i < 2; i++) {
          ah[i] = *(const bf16x8*)&Ash[wm + i * 16 + mrow][kko];
          al[i] = *(const bf16x8*)&Asl[wm + i * 16 + mrow][kko];
        }
        #pragma unroll
        for (int j = 0; j < 4; j++) {
          bh[j] = *(const bf16x8*)&Bh[(size_t)(j * 16 + mrow) * 64 + kko];
          bl[j] = *(const bf16x8*)&Bl[(size_t)(j * 16 + mrow) * 64 + kko];
        }
        #pragma unroll
        for (int i = 0; i < 2; i++)
          #pragma unroll
          for (int j = 0; j < 4; j++) {
            acc[i][j] = __builtin_amdgcn_mfma_f32_16x16x32_bf16(ah[i], bh[j], acc[i][j], 0, 0, 0);
            acc[i][j] = __builtin_amdgcn_mfma_f32_16x16x32_bf16(ah[i], bl[j], acc[i][j], 0, 0, 0);
            acc[i][j] = __builtin_amdgcn_mfma_f32_16x16x32_bf16(al[i], bh[j], acc[i][j], 0, 0, 0);
          }
      }
    }
    float* C = eparts + (size_t)z * 8192 * 256;
    int rbase = quad * 4;
    #pragma unroll
    for (int i = 0; i < 2; i++)
      #pragma unroll
      for (int j = 0; j < 4; j++) {
        int col = n0 + j * 16 + mrow;
        #pragma unroll
        for (int r = 0; r < 4; r++) {
          int row = m0 + wm + i * 16 + rbase + r;
          C[(size_t)row * 256 + col] = acc[i][j][r];
        }
      }
  } else {
    // fb GEMM: M=640, N=256, K=320, 64x64 tiles, VALU-staged split-bf16 (padded LDS)
    short (*Ash)[72] = (short (*)[72])(smem);
    short (*Asl)[72] = (short (*)[72])(smem + 9216);
    short (*Bsh)[72] = (short (*)[72])(smem + 18432);
    short (*Bsl)[72] = (short (*)[72])(smem + 27648);
    int idx = bid - 512;                  // 0..39
    int m0 = (idx % 10) * 64, n0 = (idx / 10) * 64;
    int wm = (wave & 1) * 32, wn = (wave >> 1) * 32;
    int srow = tid >> 3, sseg = (tid & 7) * 8;
    f32x4 acc[2][2];
    #pragma unroll
    for (int i = 0; i < 2; i++)
      #pragma unroll
      for (int j = 0; j < 2; j++) acc[i][j] = (f32x4){0.f, 0.f, 0.f, 0.f};

    for (int k0 = 0; k0 < 320; k0 += 64) {
      size_t aoff0 = (size_t)(m0 + srow) * 320 + k0 + sseg;
      size_t aoff1 = aoff0 + (size_t)32 * 320;
      size_t boff0 = (size_t)(n0 + srow) * 320 + k0 + sseg;
      size_t boff1 = boff0 + (size_t)32 * 320;
      bf16x8 a0h = *(const bf16x8*)(th + aoff0);
      bf16x8 a1h = *(const bf16x8*)(th + aoff1);
      bf16x8 a0l = *(const bf16x8*)(tl + aoff0);
      bf16x8 a1l = *(const bf16x8*)(tl + aoff1);
      bf16x8 b0h = *(const bf16x8*)(w2h + boff0);
      bf16x8 b1h = *(const bf16x8*)(w2h + boff1);
      bf16x8 b0l = *(const bf16x8*)(w2l + boff0);
      bf16x8 b1l = *(const bf16x8*)(w2l + boff1);
      __syncthreads();
      *(bf16x8*)&Ash[srow][sseg] = a0h;  *(bf16x8*)&Ash[srow + 32][sseg] = a1h;
      *(bf16x8*)&Asl[srow][sseg] = a0l;  *(bf16x8*)&Asl[srow + 32][sseg] = a1l;
      *(bf16x8*)&Bsh[srow][sseg] = b0h;  *(bf16x8*)&Bsh[srow + 32][sseg] = b1h;
      *(bf16x8*)&Bsl[srow][sseg] = b0l;  *(bf16x8*)&Bsl[srow + 32][sseg] = b1l;
      __syncthreads();
      #pragma unroll
      for (int ks = 0; ks < 2; ks++) {
        int kk = ks * 32 + quad * 8;
        bf16x8 ah[2], al[2], bh[2], bl[2];
        ah[0] = *(const bf16x8*)&Ash[wm + mrow][kk];
        ah[1] = *(const bf16x8*)&Ash[wm + 16 + mrow][kk];
        al[0] = *(const bf16x8*)&Asl[wm + mrow][kk];
        al[1] = *(const bf16x8*)&Asl[wm + 16 + mrow][kk];
        bh[0] = *(const bf16x8*)&Bsh[wn + mrow][kk];
        bh[1] = *(const bf16x8*)&Bsh[wn + 16 + mrow][kk];
        bl[0] = *(const bf16x8*)&Bsl[wn + mrow][kk];
        bl[1] = *(const bf16x8*)&Bsl[wn + 16 + mrow][kk];
        #pragma unroll
        for (int i = 0; i < 2; i++)
          #pragma unroll
          for (int j = 0; j < 2; j++) {
            acc[i][j] = __builtin_amdgcn_mfma_f32_16x16x32_bf16(ah[i], bh[j], acc[i][j], 0, 0, 0);
            acc[i][j] = __builtin_amdgcn_mfma_f32_16x16x32_bf16(ah[i], bl[j], acc[i][j], 0, 0, 0);
            acc[i][j] = __builtin_amdgcn_mfma_f32_16x16x32_bf16(al[i], bh[j], acc[i][j], 0, 0, 0);
          }
      }
    }
    int rbase = quad * 4;
    #pragma unroll
    for (int i = 0; i < 2; i++)
      #pragma unroll
      for (int j = 0; j < 2; j++) {
        int col = n0 + wn + j * 16 + mrow;
        #pragma unroll
        for (int r = 0; r < 4; r++) {
          int row = m0 + wm + i * 16 + rbase + r;
          fbuf[(size_t)row * 256 + col] = acc[i][j][r];
        }
      }
  }
}

// ---------- final GEMM: 128x64 tile, BK=64, LDS dbuf, counted vmcnt, XOR swizzle ----------
__global__ __launch_bounds__(256) void k_gemm_f(const short* __restrict__ A,
                                                const short* __restrict__ BT,
                                                const float* __restrict__ bias,
                                                float* __restrict__ C,
                                                int K, int ldc, int nstore) {
  __shared__ __align__(16) short As[2][128][64];  // 32 KB
  __shared__ __align__(16) short Bs[2][64][64];   // 16 KB
  int m0 = blockIdx.x * 128, n0 = blockIdx.y * 64;
  int tid = threadIdx.x, lane = tid & 63, wave = tid >> 6;
  int wm = wave * 32;
  int mrow = lane & 15, quad = lane >> 4;
  int lrow = lane >> 3;
  int lsegsw = ((lane & 7) ^ lrow) * 8;   // pre-swizzled global k-segment

  f32x4 acc[2][4];
  #pragma unroll
  for (int i = 0; i < 2; i++)
    #pragma unroll
    for (int j = 0; j < 4; j++) acc[i][j] = (f32x4){0.f, 0.f, 0.f, 0.f};

  auto stage = [&](int k0, int buf) {    // 6 vm ops per wave
    #pragma unroll
    for (int i = 0; i < 4; i++) {
      int c = wave * 4 + i;
      load_lds16(&As[buf][c * 8][0], A + (size_t)(m0 + c * 8 + lrow) * K + k0 + lsegsw);
    }
    #pragma unroll
    for (int i = 0; i < 2; i++) {
      int c = wave * 2 + i;
      load_lds16(&Bs[buf][c * 8][0], BT + (size_t)(n0 + c * 8 + lrow) * K + k0 + lsegsw);
    }
  };

  int NT = K >> 6;
  stage(0, 0);
  int rsw = mrow & 7;
  for (int t = 0; t < NT; t++) {
    int cur = t & 1;
    if (t + 1 < NT) {
      stage((t + 1) << 6, cur ^ 1);      // stays in flight across the barrier
      asm volatile("s_waitcnt vmcnt(6)" ::: "memory");   // buf[cur]'s 6 loads retired
    } else {
      asm volatile("s_waitcnt vmcnt(0)" ::: "memory");
    }
    __builtin_amdgcn_s_barrier();
    #pragma unroll
    for (int ks = 0; ks < 2; ks++) {
      int kko = (((ks * 4 + quad) ^ rsw) & 7) * 8;
      bf16x8 af[2], bf[4];
      #pragma unroll
      for (int i = 0; i < 2; i++) af[i] = *(const bf16x8*)&As[cur][wm + i * 16 + mrow][kko];
      #pragma unroll
      for (int j = 0; j < 4; j++) bf[j] = *(const bf16x8*)&Bs[cur][j * 16 + mrow][kko];
      #pragma unroll
      for (int i = 0; i < 2; i++)
        #pragma unroll
        for (int j = 0; j < 4; j++)
          acc[i][j] = __builtin_amdgcn_mfma_f32_16x16x32_bf16(af[i], bf[j], acc[i][j], 0, 0, 0);
    }
    __builtin_amdgcn_s_barrier();        // all reads of buf[cur] done before re-stage
  }
  int rbase = quad * 4;
  #pragma unroll
  for (int i = 0; i < 2; i++)
    #pragma unroll
    for (int j = 0; j < 4; j++) {
      int col = n0 + j * 16 + mrow;
      if (col < nstore) {
        float bv = bias[col];
        #pragma unroll
        for (int r = 0; r < 4; r++) {
          int row = m0 + wm + i * 16 + rbase + r;
          C[(size_t)row * ldc + col] = acc[i][j][r] + bv;
        }
      }
    }
}

// ---------- fused middle: dual split-K partials; logits via -2*w3*sigma ----------
__global__ __launch_bounds__(512) void k_middle(const float* __restrict__ e0p,
                                                const float* __restrict__ e1p,
                                                const float* __restrict__ fb,
                                                const float* __restrict__ w3,
                                                const float* __restrict__ bias,
                                                short* __restrict__ cont) {
  __shared__ __align__(16) float fbs[40 * 256];  // 40 KB: (f+bias)*TANH_SCALE
  __shared__ float lg[16][40];
  __shared__ float attn[16][40];
  int tid = threadIdx.x, wave = tid >> 6, lane = tid & 63;
  int la = lane & 31, half = lane >> 5;
  int row0 = blockIdx.x * 16;
  int b = row0 >> 9;
  int lgrow = wave + (half ? 8 : 0);
  int myrow = row0 + lgrow;

  const float4* fsrc = (const float4*)(fb + (size_t)b * 40 * 256);
  const float4* bias4 = (const float4*)bias;
  for (int i = tid; i < 40 * 64; i += 512) {
    float4 v = fsrc[i];
    float4 bb = bias4[i & 63];
    v.x = (v.x + bb.x) * TANH_SCALE; v.y = (v.y + bb.y) * TANH_SCALE;
    v.z = (v.z + bb.z) * TANH_SCALE; v.w = (v.w + bb.w) * TANH_SCALE;
    ((float4*)fbs)[i] = v;
  }
  __syncthreads();

  int a0 = la * 8;
  size_t eoff = (size_t)myrow * 256 + a0;
  float4 p00 = *(const float4*)(e0p + eoff);
  float4 p01 = *(const float4*)(e0p + eoff + 4);
  float4 p10 = *(const float4*)(e1p + eoff);
  float4 p11 = *(const float4*)(e1p + eoff + 4);
  float4 e0, e1;
  e0.x = p00.x + p10.x; e0.y = p00.y + p10.y; e0.z = p00.z + p10.z; e0.w = p00.w + p10.w;
  e1.x = p01.x + p11.x; e1.y = p01.y + p11.y; e1.z = p01.z + p11.z; e1.w = p01.w + p11.w;
  float4 w30 = *(const float4*)(w3 + a0);
  float4 w31 = *(const float4*)(w3 + a0 + 4);
  w30.x *= -2.f; w30.y *= -2.f; w30.z *= -2.f; w30.w *= -2.f;
  w31.x *= -2.f; w31.y *= -2.f; w31.z *= -2.f; w31.w *= -2.f;
  float4 bv0 = *(const float4*)(bias + a0);
  float4 bv1 = *(const float4*)(bias + a0 + 4);
  float4 es0, es1;
  es0.x = e0.x * TANH_SCALE; es0.y = e0.y * TANH_SCALE;
  es0.z = e0.z * TANH_SCALE; es0.w = e0.w * TANH_SCALE;
  es1.x = e1.x * TANH_SCALE; es1.y = e1.y * TANH_SCALE;
  es1.z = e1.z * TANH_SCALE; es1.w = e1.w * TANH_SCALE;

  for (int tc = 0; tc < 40; tc += 4) {
    float p[4];
    #pragma unroll
    for (int u = 0; u < 4; u++) {
      const float* fr = &fbs[(tc + u) * 256 + a0];
      float4 f0 = *(const float4*)fr;
      float4 f1 = *(const float4*)(fr + 4);
      p[u] = sig_pre(es0.x + f0.x) * w30.x + sig_pre(es0.y + f0.y) * w30.y
           + sig_pre(es0.z + f0.z) * w30.z + sig_pre(es0.w + f0.w) * w30.w
           + sig_pre(es1.x + f1.x) * w31.x + sig_pre(es1.y + f1.y) * w31.y
           + sig_pre(es1.z + f1.z) * w31.z + sig_pre(es1.w + f1.w) * w31.w;
    }
    #pragma unroll
    for (int s = 16; s >= 1; s >>= 1) {
      #pragma unroll
      for (int u = 0; u < 4; u++) p[u] += __shfl_xor(p[u], s, 64);
    }
    if (la == 0) {
      #pragma unroll
      for (int u = 0; u < 4; u++) lg[lgrow][tc + u] = p[u];
    }
  }

  auto softmax_row = [&](int r) {
    float x = (lane < 40) ? lg[r][lane] : -3.0e38f;
    float m = x;
    #pragma unroll
    for (int s = 32; s >= 1; s >>= 1) m = fmaxf(m, __shfl_xor(m, s, 64));
    float ex = (lane < 40) ? __builtin_amdgcn_exp2f((x - m) * 1.4426950408889634f) : 0.f;
    float ssum = ex;
    #pragma unroll
    for (int s = 32; s >= 1; s >>= 1) ssum += __shfl_xor(ssum, s, 64);
    if (lane < 40) attn[r][lane] = ex * __builtin_amdgcn_rcpf(ssum);
  };
  softmax_row(wave);
  softmax_row(wave + 8);

  float ac[8] = {0.f,0.f,0.f,0.f,0.f,0.f,0.f,0.f};
  for (int t = 0; t < 40; t++) {
    float w = attn[lgrow][t];
    const float* fr = &fbs[t * 256 + a0];
    float4 f0 = *(const float4*)fr;
    float4 f1 = *(const float4*)(fr + 4);
    ac[0] += w * f0.x; ac[1] += w * f0.y; ac[2] += w * f0.z; ac[3] += w * f0.w;
    ac[4] += w * f1.x; ac[5] += w * f1.y; ac[6] += w * f1.z; ac[7] += w * f1.w;
  }
  float tx[8];
  tx[0] = ac[0] * TANH_UNSCALE - bv0.x; tx[1] = ac[1] * TANH_UNSCALE - bv0.y;
  tx[2] = ac[2] * TANH_UNSCALE - bv0.z; tx[3] = ac[3] * TANH_UNSCALE - bv0.w;
  tx[4] = ac[4] * TANH_UNSCALE - bv1.x; tx[5] = ac[5] * TANH_UNSCALE - bv1.y;
  tx[6] = ac[6] * TANH_UNSCALE - bv1.z; tx[7] = ac[7] * TANH_UNSCALE - bv1.w;
  float ev[8] = {e0.x, e0.y, e0.z, e0.w, e1.x, e1.y, e1.z, e1.w};

  short* crow = cont + (size_t)myrow * 1024 + a0;
  auto st8 = [&](int off, const float* v) {
    bf16x8 pk;
    #pragma unroll
    for (int i = 0; i < 8; i++) pk[i] = cvt_bf16(v[i]);
    *(bf16x8*)(crow + off) = pk;
  };
  float s0[8], s1[8], s2[8], s3[8];
  #pragma unroll
  for (int i = 0; i < 8; i++) {
    s0[i] = tanh_fast(ev[i]);
    s1[i] = tanh_fast(tx[i]);
    s2[i] = tanh_fast(ev[i] * tx[i]);
    s3[i] = tanh_fast(ev[i] - tx[i]);
  }
  st8(0, s0); st8(256, s1); st8(512, s2); st8(768, s3);
}

extern "C" void kernel_launch(void* const* d_in, const int* in_sizes, int n_in,
                              void* d_out, int out_size, void* d_ws, size_t ws_size,
                              hipStream_t stream) {
  const float* video = (const float*)d_in[0];  // 16x512x1024
  const float* text  = (const float*)d_in[1];  // 16x40x300
  const float* w1    = (const float*)d_in[2];  // 1024x256
  const float* w2    = (const float*)d_in[3];  // 300x256
  const float* w3    = (const float*)d_in[4];  // 256
  const float* bias  = (const float*)d_in[5];  // 256
  const float* w4    = (const float*)d_in[6];  // 1024x500
  const float* b4    = (const float*)d_in[7];  // 500
  float* out = (float*)d_out;                  // 16x512x500
  char* ws = (char*)d_ws;

  short* contbuf  = (short*)(ws);                        // 8192x1024 bf16 = 16,777,216
  short* w1T_hi   = (short*)(ws + 16777216);             // 256x1024 bf16 = 524,288
  short* w1T_lo   = (short*)(ws + 17301504);             // 524,288
  short* w4T      = (short*)(ws + 17825792);             // 512x1024 bf16 = 1,048,576
  float* fbuf     = (float*)(ws + 18874368);             // 16x40x256 f32 = 655,360
  float* eparts   = (float*)(ws + 19529728);             // 2 x 8192x256 f32 = 16,777,216
  float* epart1   = (float*)(ws + 19529728 + 8388608);
  short* text_hi  = (short*)(ws + 36306944);             // 640x320 bf16 = 409,600
  short* text_lo  = (short*)(ws + 36716544);             // 409,600
  short* w2T_hi   = (short*)(ws + 37126144);             // 256x320 bf16 = 204,800
  short* w2T_lo   = (short*)(ws + 37330944);             // 204,800

  k_prep<<<1008, 256, 0, stream>>>(text, w1, w2, w4,
                                   w1T_hi, w1T_lo, w4T,
                                   text_hi, text_lo, w2T_hi, w2T_lo);
  k_gemm_big<<<552, 256, 0, stream>>>(video, w1T_hi, w1T_lo,
                                      text_hi, text_lo, w2T_hi, w2T_lo,
                                      eparts, fbuf);
  k_middle<<<512, 512, 0, stream>>>(eparts, epart1, fbuf, w3, bias, contbuf);
  k_gemm_f<<<dim3(64, 8), 256, 0, stream>>>(contbuf, w4T, b4, out, 1024, 500, 500);
}